// Round 8
// baseline (181.013 us; speedup 1.0000x reference)
//
#include <hip/hip_runtime.h>
#include <hip/hip_bf16.h>

typedef __attribute__((ext_vector_type(8))) short short8;
typedef __attribute__((ext_vector_type(4))) short short4v;
typedef __attribute__((ext_vector_type(4))) float f32x4;

// __float2bfloat16 emits a single HW cvt op on gfx950 (R8: bit-trick regressed).
__device__ __forceinline__ unsigned short f2bf(float f) {
  union { __hip_bfloat16 h; unsigned short u; } cv;
  cv.h = __float2bfloat16(f);
  return cv.u;
}

__device__ __forceinline__ void gld16(const void* g, void* l) {
  __builtin_amdgcn_global_load_lds(
      (const __attribute__((address_space(1))) unsigned int*)g,
      (__attribute__((address_space(3))) unsigned int*)l, 16, 0, 0);
}

__device__ __forceinline__ f32x4 mfma_bf16(short8 a, short8 b, f32x4 c) {
  return __builtin_amdgcn_mfma_f32_16x16x32_bf16(a, b, c, 0, 0, 0);
}

#define QSCALE 0.18033688011112042f  /* 0.125 * log2(e): scores in log2 domain */
#define L2E    1.4426950408889634f

// ---------------------------------------------------------------- prep ----
// One launch: blocks [0,4096) cast X fp32->bf16; blocks [4096,5120) transpose
// weights (first 768: w_attn 64-col strips; last 256: w_proj).
// R18: w_proj's contraction index (h*64+d) stored pi-permuted within each
// 64-block: p = (d&15)*4 + (d>>4) — matches flash's pi-permuted ctx stores
// (both GEMM operands permuted identically -> contraction invariant).
__global__ void prep(const float* __restrict__ x, unsigned short* __restrict__ xbf,
                     const float* __restrict__ wa, unsigned short* __restrict__ da,
                     const float* __restrict__ wp, unsigned short* __restrict__ dp) {
  __shared__ float tile[64][65];
  const int t = threadIdx.x;
  const int bid = blockIdx.x;
  if (bid < 4096) {
    int i = bid * 256 + t;
    float4 v = ((const float4*)x)[i];
    ushort4 o;
    o.x = f2bf(v.x); o.y = f2bf(v.y); o.z = f2bf(v.z); o.w = f2bf(v.w);
    ((ushort4*)xbf)[i] = o;
    return;
  }
  int idx = bid - 4096;          // 0..1023
  const int tr = idx & 15;       // 16 row-strips of 64
  int y = idx >> 4;              // 0..63
  const float* src;
  unsigned short* dst;
  int C;
  if (y < 48) { src = wa; dst = da; C = 3072; }
  else        { src = wp; dst = dp; C = 1024; y -= 48; }
  const int pflag = (C == 1024);  // pi-permute only w_proj
  const int tc = y;  // block-uniform
#pragma unroll
  for (int i = 0; i < 16; ++i) {
    int id2 = t + i * 256;
    int lr = id2 >> 6, lc = id2 & 63;
    tile[lr][lc] = src[(size_t)(tr * 64 + lr) * C + tc * 64 + lc];
  }
  __syncthreads();
#pragma unroll
  for (int i = 0; i < 16; ++i) {
    int id2 = t + i * 256;
    int lr = id2 >> 6, lc = id2 & 63;
    int lcs = pflag ? ((lc & 15) * 4 + (lc >> 4)) : lc;  // pi within 64-block
    dst[(size_t)(tc * 64 + lr) * 1024 + tr * 64 + lcs] = f2bf(tile[lc][lr]);
  }
}

// ---------------------------------------------------------------- GEMM ----
// Unified QKV GEMM: grid (32, 24) = 768 blocks (3/CU).
// R18: double-buffered single-barrier K-loop (stage(kt+1) issued BEFORE
// compute(kt); barrier drain covered by the compute phase; 32 barriers not 64;
// staging addresses are incrementing pointers).
// nbase<2048 -> Q/K epilogue now COALESCED: rows stored pi-permuted
// (p=(d&15)*4+(d>>4)) so each thread writes short4 (8B, 128B/16-lane line)
// instead of 64 scattered 2B stores. Flash is invariant: Q and K pass through
// identical opaque-chunk staging, so permuting both contraction operands
// identically leaves S unchanged.
// nbase>=2048 -> V path unchanged: tau64-permuted V' [bh][d][2048],
// stored pos (per 64-block) = 32*s5 + 8*((s>>2)&3) + 4*s4 + (s&3).
__global__ __launch_bounds__(256, 2) void gemm_qkv(
    const short* __restrict__ A, const short* __restrict__ Bt, const float* __restrict__ bias,
    unsigned short* __restrict__ q, unsigned short* __restrict__ k,
    unsigned short* __restrict__ vt) {
  __shared__ __align__(16) char smem[32768];
  // A0 [0,8K) A1 [8K,16K) B0 [16K,24K) B1 [24K,32K)
  char* const A0 = smem;
  char* const A1 = smem + 8192;
  char* const B0 = smem + 16384;
  char* const B1 = smem + 24576;
  unsigned short* vlds = (unsigned short*)smem;  // [64 d][136] permuted s (V epilogue)
  const int t = threadIdx.x;
  const int wave = t >> 6, lane = t & 63;
  const int quad = lane >> 4, l16 = lane & 15;
  const int wm = (wave >> 1) * 64, wn = (wave & 1) * 64;
  const int mbase = blockIdx.x * 128, nbase = blockIdx.y * 128;
  f32x4 acc[4][4];
#pragma unroll
  for (int i = 0; i < 4; ++i)
#pragma unroll
    for (int j = 0; j < 4; ++j) acc[i][j] = (f32x4)0.0f;

  // staging source pointers (advance +32 shorts per kt)
  const short* ap[2];
  const short* bp[2];
#pragma unroll
  for (int i = 0; i < 2; ++i) {
    int c = t + i * 256;
    int row = c >> 2, c4 = c & 3;
    ap[i] = A + (size_t)(mbase + row) * 1024 + c4 * 8;
    bp[i] = Bt + (size_t)(nbase + row) * 1024 + c4 * 8;
  }
  auto stg = [&](char* as, char* bs) {
#pragma unroll
    for (int i = 0; i < 2; ++i) {
      int c = t + i * 256;
      gld16(ap[i], as + c * 16);
      gld16(bp[i], bs + c * 16);
    }
    ap[0] += 32; ap[1] += 32; bp[0] += 32; bp[1] += 32;
  };
  auto cmp = [&](const char* as, const char* bs) {
    short8 af[4], bf[4];
#pragma unroll
    for (int m = 0; m < 4; ++m)
      af[m] = *(const short8*)(as + (wm + m * 16 + l16) * 64 + quad * 16);
#pragma unroll
    for (int n = 0; n < 4; ++n)
      bf[n] = *(const short8*)(bs + (wn + n * 16 + l16) * 64 + quad * 16);
#pragma unroll
    for (int m = 0; m < 4; ++m)
#pragma unroll
      for (int n = 0; n < 4; ++n)
        acc[m][n] = mfma_bf16(af[m], bf[n], acc[m][n]);
  };

  stg(A0, B0);
  __syncthreads();
#pragma unroll 1
  for (int kt = 0; kt < 32; kt += 2) {
    stg(A1, B1);         // stage kt+1 (issued before compute -> drain covered)
    cmp(A0, B0);         // compute kt
    __syncthreads();
    if (kt + 2 < 32) stg(A0, B0);  // stage kt+2
    cmp(A1, B1);         // compute kt+1
    __syncthreads();
  }

  if (nbase < 2048) {
    // ---- Q/K coalesced epilogue (pi-permuted rows) ----
    const int colbase = nbase + wn;             // multiple of 64
    const int which = colbase >> 10;            // 0=Q, 1=K
    const int h = (colbase & 1023) >> 6;
    unsigned short* dst = which ? k : q;
    const float scale = which ? 1.0f : QSCALE;
    float bc[4];
#pragma unroll
    for (int n = 0; n < 4; ++n) bc[n] = bias[colbase + n * 16 + l16];
#pragma unroll
    for (int m = 0; m < 4; ++m) {
#pragma unroll
      for (int r = 0; r < 4; ++r) {
        int row = mbase + wm + m * 16 + quad * 4 + r;
        int b = row >> 11, s = row & 2047;
        short4v o;
#pragma unroll
        for (int n = 0; n < 4; ++n)
          o[n] = (short)f2bf((acc[m][n][r] + bc[n]) * scale);
        // stored pos of d=n*16+l16 is l16*4+n -> contiguous short4 per thread
        *(short4v*)&dst[(((size_t)(b * 16 + h)) * 2048 + s) * 64 + l16 * 4] = o;
      }
    }
  } else {
    // ---- V transpose epilogue: tau64 per 64-block ----
    const int b = mbase >> 11, s0 = mbase & 2047;
    const int vcb = nbase - 2048;  // 0..895, v-column base
    __syncthreads();               // hard fence before vlds reuses the stage region
#pragma unroll
    for (int half = 0; half < 2; ++half) {
      if (wn == half * 64) {
#pragma unroll
        for (int n = 0; n < 4; ++n) {
          int col_l = n * 16 + l16;  // d 0..63
          float bc = bias[nbase + half * 64 + col_l];
#pragma unroll
          for (int m = 0; m < 4; ++m)
#pragma unroll
            for (int r = 0; r < 4; ++r) {
              int row_l = wm + m * 16 + quad * 4 + r;  // s_local 0..127
              int idx = (row_l & 64) + ((row_l >> 5) & 1) * 32 +
                        ((row_l >> 2) & 3) * 8 + ((row_l >> 4) & 1) * 4 + (row_l & 3);
              vlds[col_l * 136 + idx] = f2bf(acc[m][n][r] + bc);
            }
        }
      }
      __syncthreads();
      int h = (vcb + half * 64) >> 6;  // head 0..15
      size_t obase = ((size_t)(b * 16 + h)) * 64 * 2048;
#pragma unroll
      for (int i = 0; i < 4; ++i) {
        int c = t + i * 256;
        int d_l = c >> 4, c16 = c & 15;
        short8 v = *(const short8*)&vlds[d_l * 136 + c16 * 8];
        *(short8*)&vt[obase + (size_t)d_l * 2048 + s0 + c16 * 8] = v;
      }
      __syncthreads();
    }
  }
}

// Proj: 64x128 tiles, grid (64,8) = 512 blocks (2/CU).
// R18: same double-buffered single-barrier K-loop as gemm_qkv. Inputs (ctx,
// Wprj_t) are pi-permuted in the contraction dim (both sides identically).
__global__ __launch_bounds__(256, 2) void gemm_proj(
    const short* __restrict__ A, const short* __restrict__ Bt, const float* __restrict__ bias,
    float* __restrict__ out) {
  __shared__ __align__(16) char smem[24576];
  // A0 [0,4K) A1 [4K,8K) B0 [8K,16K) B1 [16K,24K)
  char* const A0 = smem;
  char* const A1 = smem + 4096;
  char* const B0 = smem + 8192;
  char* const B1 = smem + 16384;
  const int t = threadIdx.x;
  const int wave = t >> 6, lane = t & 63;
  const int quad = lane >> 4, l16 = lane & 15;
  const int wm = (wave >> 1) * 32, wn = (wave & 1) * 64;
  const int mbase = blockIdx.x * 64, nbase = blockIdx.y * 128;
  f32x4 acc[2][4];
#pragma unroll
  for (int i = 0; i < 2; ++i)
#pragma unroll
    for (int j = 0; j < 4; ++j) acc[i][j] = (f32x4)0.0f;

  const short* ap;
  const short* bp[2];
  {
    int row = t >> 2, c4 = t & 3;
    ap = A + (size_t)(mbase + row) * 1024 + c4 * 8;
  }
#pragma unroll
  for (int i = 0; i < 2; ++i) {
    int c = t + i * 256;
    int row = c >> 2, c4 = c & 3;
    bp[i] = Bt + (size_t)(nbase + row) * 1024 + c4 * 8;
  }
  auto stg = [&](char* as, char* bs) {
    gld16(ap, as + t * 16);
#pragma unroll
    for (int i = 0; i < 2; ++i) gld16(bp[i], bs + (t + i * 256) * 16);
    ap += 32; bp[0] += 32; bp[1] += 32;
  };
  auto cmp = [&](const char* as, const char* bs) {
    short8 af[2], bf[4];
#pragma unroll
    for (int m = 0; m < 2; ++m)
      af[m] = *(const short8*)(as + (wm + m * 16 + l16) * 64 + quad * 16);
#pragma unroll
    for (int n = 0; n < 4; ++n)
      bf[n] = *(const short8*)(bs + (wn + n * 16 + l16) * 64 + quad * 16);
#pragma unroll
    for (int m = 0; m < 2; ++m)
#pragma unroll
      for (int n = 0; n < 4; ++n)
        acc[m][n] = mfma_bf16(af[m], bf[n], acc[m][n]);
  };

  stg(A0, B0);
  __syncthreads();
#pragma unroll 1
  for (int kt = 0; kt < 32; kt += 2) {
    stg(A1, B1);
    cmp(A0, B0);
    __syncthreads();
    if (kt + 2 < 32) stg(A0, B0);
    cmp(A1, B1);
    __syncthreads();
  }

#pragma unroll
  for (int n = 0; n < 4; ++n) {
    int col = nbase + wn + n * 16 + l16;
    float bc = bias[col];
#pragma unroll
    for (int m = 0; m < 2; ++m)
#pragma unroll
      for (int r = 0; r < 4; ++r) {
        int row = mbase + wm + m * 16 + quad * 4 + r;
        out[(size_t)row * 1024 + col] = acc[m][n][r] + bc;
      }
  }
}

// ---------------------------------------------------------------- flash ----
// R18 = R16 (best measured: 48.5us) + pi-permuted ctx stores (short4 not 2B).
// 3-buffer 2-ahead pipeline with counted vmcnt: stage(kt+2) issued during
// iter kt; top of iter kt waits vmcnt(4) (stage(kt+1) stays in flight across
// the barrier — targets loads issued TWO iterations ago). mask loads kept
// OLDER than stage in the vmcnt queue via sched_barrier. Swapped-QK
// in-register softmax (no P in LDS), tau64 V', KVBLK=64, Br=128, grid (32,16).
__global__ __launch_bounds__(256, 2) void flash_attn(
    const short* __restrict__ Qg, const short* __restrict__ Kg, const short* __restrict__ Vtg,
    const float* __restrict__ mask, unsigned short* __restrict__ ctx) {
  __shared__ __align__(16) unsigned char smem[49152];
  // K bufs: [0,24576) three 8K; V bufs: [24576,49152) three 8K
  const int t = threadIdx.x;  // 0..255
  const int wave = t >> 6, lane = t & 63;
  const int quad = lane >> 4, l16 = lane & 15;
  const int bh = blockIdx.x, b = bh >> 4, h = bh & 15;
  const int qbase = blockIdx.y * 128;
  const size_t bh_off = (size_t)bh * 2048 * 64;

  // ---- Q stage (16 KB, overlaps Kbuf0/Kbuf1 region), then to registers ----
#pragma unroll
  for (int i = 0; i < 4; ++i) {
    int c = t + i * 256;
    int row = c >> 3, col = c & 7;
    gld16(Qg + bh_off + (size_t)(qbase + row) * 64 + (col ^ (row & 7)) * 8,
          (char*)smem + c * 16);
  }
  __syncthreads();
  short8 qf[2][2];  // [m-frag][ks]
#pragma unroll
  for (int mf = 0; mf < 2; ++mf)
#pragma unroll
    for (int ks = 0; ks < 2; ++ks) {
      int row = wave * 32 + mf * 16 + l16;
      qf[mf][ks] = *(const short8*)((const char*)smem +
                                    (row * 8 + ((ks * 4 + quad) ^ (l16 & 7))) * 16);
    }
  __syncthreads();  // all waves done reading Q before K staging reuses region

  // ---- loop-invariant LDS byte offsets (VGPR-resident) ----
  int koff[2][4];  // [ks][n]
#pragma unroll
  for (int ks = 0; ks < 2; ++ks)
#pragma unroll
    for (int n = 0; n < 4; ++n) {
      int row = n * 16 + l16;
      koff[ks][n] = (row * 8 + ((ks * 4 + quad) ^ (l16 & 7))) * 16;
    }
  int voff[2][4];  // [ks][db]
#pragma unroll
  for (int ks = 0; ks < 2; ++ks)
#pragma unroll
    for (int db = 0; db < 4; ++db) {
      int d = db * 16 + l16;
      voff[ks][db] = d * 128 + (((ks * 4 + quad) ^ (d & 7)) * 16);
    }

  // ---- staging source pointers (increment by constants each stage) ----
  const short* kgp[2];
  const short* vgp[2];
#pragma unroll
  for (int i = 0; i < 2; ++i) {
    int c = t + i * 256;
    int row = c >> 3, col = c & 7;
    kgp[i] = Kg + bh_off + (size_t)row * 64 + (col ^ (row & 7)) * 8;
    vgp[i] = Vtg + ((size_t)bh * 64 + row) * 2048 + (col ^ (row & 7)) * 8;
  }
  const float* mpt = mask + b * 2048 + quad * 4;

  auto stage_to = [&](char* kd, char* vd) {
#pragma unroll
    for (int i = 0; i < 2; ++i) {
      gld16(kgp[i], kd + (t + i * 256) * 16);
      gld16(vgp[i], vd + (t + i * 256) * 16);
    }
    kgp[0] += 4096; kgp[1] += 4096;  // 64 rows x 64 shorts
    vgp[0] += 64;   vgp[1] += 64;    // 64 shorts along s
  };

  f32x4 O[2][4];
  float l_part[2];
#pragma unroll
  for (int mf = 0; mf < 2; ++mf)
#pragma unroll
    for (int d = 0; d < 4; ++d) O[mf][d] = (f32x4)0.0f;
  l_part[0] = 0.0f;
  l_part[1] = 0.0f;

  char* const KB[3] = {(char*)smem, (char*)smem + 8192, (char*)smem + 16384};
  char* const VB[3] = {(char*)smem + 24576, (char*)smem + 32768, (char*)smem + 40960};

  // iteration body: barrier (caller does the vmcnt wait), mask, optional
  // stage(kt+2), QK, in-register softmax, PV. No trailing barrier.
  auto iter_body = [&](const char* Kc, const char* Vc, char* ksd, char* vsd,
                       bool doStage) {
    __builtin_amdgcn_s_barrier();
    __builtin_amdgcn_sched_barrier(0);  // no ds_read of buf[kt] above barrier

    float4 mq[4];
#pragma unroll
    for (int n = 0; n < 4; ++n) mq[n] = *(const float4*)(mpt + n * 16);
    mpt += 64;
    __builtin_amdgcn_sched_barrier(0);  // mask loads stay OLDER than stage

    if (doStage) stage_to(ksd, vsd);

    // ---- S^T = K @ Q^T (log2 domain); kf feeds BOTH m-frags ----
    f32x4 sa[2][4];
    __builtin_amdgcn_s_setprio(1);
#pragma unroll
    for (int n = 0; n < 4; ++n) {
      short8 kf = *(const short8*)(Kc + koff[0][n]);
      sa[0][n] = mfma_bf16(kf, qf[0][0], (f32x4)0.0f);
      sa[1][n] = mfma_bf16(kf, qf[1][0], (f32x4)0.0f);
    }
#pragma unroll
    for (int n = 0; n < 4; ++n) {
      short8 kf = *(const short8*)(Kc + koff[1][n]);
      sa[0][n] = mfma_bf16(kf, qf[0][1], sa[0][n]);
      sa[1][n] = mfma_bf16(kf, qf[1][1], sa[1][n]);
    }
    __builtin_amdgcn_s_setprio(0);

    // ---- softmax fully in-register: lane owns q=l16, k = n*16+quad*4+r ----
    short8 pa[2][2];
#pragma unroll
    for (int mf = 0; mf < 2; ++mf) {
      float rs = 0.0f;
#pragma unroll
      for (int n = 0; n < 4; ++n) {
#pragma unroll
        for (int r = 0; r < 4; ++r) {
          float p = __builtin_amdgcn_exp2f(__builtin_fmaf(mq[n][r], L2E, sa[mf][n][r]));
          rs += p;
          pa[mf][n >> 1][(n & 1) * 4 + r] = (short)f2bf(p);
        }
      }
      l_part[mf] += rs;
    }

    // ---- O += P @ V' (vf feeds BOTH m-frags) ----
    __builtin_amdgcn_s_setprio(1);
#pragma unroll
    for (int ks = 0; ks < 2; ++ks) {
#pragma unroll
      for (int db = 0; db < 4; ++db) {
        short8 vf = *(const short8*)(Vc + voff[ks][db]);
        O[0][db] = mfma_bf16(pa[0][ks], vf, O[0][db]);
        O[1][db] = mfma_bf16(pa[1][ks], vf, O[1][db]);
      }
    }
    __builtin_amdgcn_s_setprio(0);
  };

  // prologue: stage kt=0 and kt=1 (8 vmem ops outstanding)
  stage_to(KB[0], VB[0]);
  stage_to(KB[1], VB[1]);

#define VMW4 asm volatile("s_waitcnt vmcnt(4)" ::: "memory")
#define VMW0 asm volatile("s_waitcnt vmcnt(0)" ::: "memory")

#pragma unroll 1
  for (int kt3 = 0; kt3 < 30; kt3 += 3) {
    VMW4; iter_body(KB[0], VB[0], KB[2], VB[2], true);
    VMW4; iter_body(KB[1], VB[1], KB[0], VB[0], true);
    VMW4; iter_body(KB[2], VB[2], KB[1], VB[1], true);
  }
  // kt = 30 (buf 0, stage(32) doesn't exist), kt = 31 (buf 1, full drain)
  VMW4; iter_body(KB[0], VB[0], nullptr, nullptr, false);
  VMW0; iter_body(KB[1], VB[1], nullptr, nullptr, false);

#undef VMW4
#undef VMW0

  // ---- l reduce: sum over quads (lane bits 4,5), then transpose to O layout ----
  float lr[2];
#pragma unroll
  for (int mf = 0; mf < 2; ++mf) {
    float l = l_part[mf];
    l += __shfl_xor(l, 16);
    l += __shfl_xor(l, 32);
    lr[mf] = l;  // valid for q = l16 (all quads hold it)
  }
  // ctx stored pi-permuted within the head 64-block: pos(d=db*16+l16)=l16*4+db
  // -> one short4 (8B) per (mf,r); proj's B (Wprj_t) is permuted identically.
#pragma unroll
  for (int mf = 0; mf < 2; ++mf) {
#pragma unroll
    for (int r = 0; r < 4; ++r) {
      float lq = __shfl(lr[mf], quad * 4 + r);  // l for q-local = quad*4+r
      float inv = 1.0f / lq;
      int s = qbase + wave * 32 + mf * 16 + quad * 4 + r;
      size_t o = ((size_t)b * 2048 + s) * 1024 + h * 64;
      short4v o4;
#pragma unroll
      for (int db = 0; db < 4; ++db)
        o4[db] = (short)f2bf(O[mf][db][r] * inv);
      *(short4v*)&ctx[o + l16 * 4] = o4;
    }
  }
}

// ---------------------------------------------------------------- launch ----
extern "C" void kernel_launch(void* const* d_in, const int* in_sizes, int n_in,
                              void* d_out, int out_size, void* d_ws, size_t ws_size,
                              hipStream_t stream) {
  const float* x      = (const float*)d_in[0];
  const float* mask   = (const float*)d_in[1];
  const float* w_attn = (const float*)d_in[2];
  const float* b_attn = (const float*)d_in[3];
  const float* w_proj = (const float*)d_in[4];
  const float* b_proj = (const float*)d_in[5];
  float* out = (float*)d_out;

  char* ws = (char*)d_ws;
  const size_t MB = 1024 * 1024;
  short*          Xbf    = (short*)(ws);                     // 8 MB, reused as ctx
  short*          Wqkv_t = (short*)(ws + 8 * MB);            // 6 MB
  short*          Wprj_t = (short*)(ws + 14 * MB);           // 2 MB
  unsigned short* Qb     = (unsigned short*)(ws + 16 * MB);  // 8 MB
  unsigned short* Kb     = (unsigned short*)(ws + 24 * MB);  // 8 MB
  unsigned short* Vtb    = (unsigned short*)(ws + 32 * MB);  // 8 MB
  unsigned short* ctx    = (unsigned short*)Xbf;

  prep<<<5120, 256, 0, stream>>>(x, (unsigned short*)Xbf,
                                 w_attn, (unsigned short*)Wqkv_t,
                                 w_proj, (unsigned short*)Wprj_t);
  gemm_qkv<<<dim3(32, 24), 256, 0, stream>>>(Xbf, Wqkv_t, b_attn, Qb, Kb, Vtb);
  flash_attn<<<dim3(32, 16), 256, 0, stream>>>((const short*)Qb, (const short*)Kb,
                                               (const short*)Vtb, mask, ctx);
  gemm_proj<<<dim3(64, 8), 256, 0, stream>>>((const short*)ctx, Wprj_t, b_proj, out);
}

// Round 9
// 178.504 us; speedup vs baseline: 1.0141x; 1.0141x over previous
//
#include <hip/hip_runtime.h>
#include <hip/hip_bf16.h>

typedef __attribute__((ext_vector_type(8))) short short8;
typedef __attribute__((ext_vector_type(4))) float f32x4;

// __float2bfloat16 emits a single HW cvt op on gfx950 (R8: bit-trick regressed).
__device__ __forceinline__ unsigned short f2bf(float f) {
  union { __hip_bfloat16 h; unsigned short u; } cv;
  cv.h = __float2bfloat16(f);
  return cv.u;
}

__device__ __forceinline__ void gld16(const void* g, void* l) {
  __builtin_amdgcn_global_load_lds(
      (const __attribute__((address_space(1))) unsigned int*)g,
      (__attribute__((address_space(3))) unsigned int*)l, 16, 0, 0);
}

__device__ __forceinline__ f32x4 mfma_bf16(short8 a, short8 b, f32x4 c) {
  return __builtin_amdgcn_mfma_f32_16x16x32_bf16(a, b, c, 0, 0, 0);
}

#define QSCALE 0.18033688011112042f  /* 0.125 * log2(e): scores in log2 domain */
#define L2E    1.4426950408889634f

// ---------------------------------------------------------------- prep ----
// One launch: blocks [0,4096) cast X fp32->bf16; blocks [4096,5120) transpose
// weights (first 768: w_attn 64-col strips; last 256: w_proj).
__global__ void prep(const float* __restrict__ x, unsigned short* __restrict__ xbf,
                     const float* __restrict__ wa, unsigned short* __restrict__ da,
                     const float* __restrict__ wp, unsigned short* __restrict__ dp) {
  __shared__ float tile[64][65];
  const int t = threadIdx.x;
  const int bid = blockIdx.x;
  if (bid < 4096) {
    int i = bid * 256 + t;
    float4 v = ((const float4*)x)[i];
    ushort4 o;
    o.x = f2bf(v.x); o.y = f2bf(v.y); o.z = f2bf(v.z); o.w = f2bf(v.w);
    ((ushort4*)xbf)[i] = o;
    return;
  }
  int idx = bid - 4096;          // 0..1023
  const int tr = idx & 15;       // 16 row-strips of 64
  int y = idx >> 4;              // 0..63
  const float* src;
  unsigned short* dst;
  int C;
  if (y < 48) { src = wa; dst = da; C = 3072; }
  else        { src = wp; dst = dp; C = 1024; y -= 48; }
  const int tc = y;  // block-uniform
#pragma unroll
  for (int i = 0; i < 16; ++i) {
    int id2 = t + i * 256;
    int lr = id2 >> 6, lc = id2 & 63;
    tile[lr][lc] = src[(size_t)(tr * 64 + lr) * C + tc * 64 + lc];
  }
  __syncthreads();
#pragma unroll
  for (int i = 0; i < 16; ++i) {
    int id2 = t + i * 256;
    int lr = id2 >> 6, lc = id2 & 63;
    dst[(size_t)(tc * 64 + lr) * 1024 + tr * 64 + lc] = f2bf(tile[lc][lr]);
  }
}

// ---------------------------------------------------------------- GEMM ----
template <int KDIM>
__device__ __forceinline__ void gemm_core(const short* __restrict__ A, const short* __restrict__ Bt,
                                          int mbase, int nbase, short* As, short* Bs,
                                          int wm, int wn, int quad, int l16, int t,
                                          f32x4 (&acc)[4][4]) {
  for (int kt = 0; kt < KDIM / 32; ++kt) {
#pragma unroll
    for (int i = 0; i < 2; ++i) {
      int c = t + i * 256;
      int row = c >> 2, c4 = c & 3;
      gld16(A + (size_t)(mbase + row) * KDIM + kt * 32 + c4 * 8, (char*)As + c * 16);
      gld16(Bt + (size_t)(nbase + row) * KDIM + kt * 32 + c4 * 8, (char*)Bs + c * 16);
    }
    __syncthreads();
    short8 af[4], bf[4];
#pragma unroll
    for (int m = 0; m < 4; ++m)
      af[m] = *(const short8*)((const char*)As + (wm + m * 16 + l16) * 64 + quad * 16);
#pragma unroll
    for (int n = 0; n < 4; ++n)
      bf[n] = *(const short8*)((const char*)Bs + (wn + n * 16 + l16) * 64 + quad * 16);
#pragma unroll
    for (int m = 0; m < 4; ++m)
#pragma unroll
      for (int n = 0; n < 4; ++n)
        acc[m][n] = mfma_bf16(af[m], bf[n], acc[m][n]);
    __syncthreads();
  }
}

// Unified QKV GEMM: grid (32, 24) = 768 blocks (3/CU). nbase<2048 -> Q/K scatter
// (Q pre-scaled by QSCALE for log2-domain flash); nbase>=2048 -> V path with
// LDS-transpose epilogue emitting V' tau64-permuted [bh][d][2048]:
// stored pos (per 64-block) = 32*s5 + 8*((s>>2)&3) + 4*s4 + (s&3).
// tau64 matches flash's in-register P packing (swapped-QK S^T frags pack
// in-lane into PV A-operands with NO cross-lane moves).
__global__ __launch_bounds__(256, 2) void gemm_qkv(
    const short* __restrict__ A, const short* __restrict__ Bt, const float* __restrict__ bias,
    unsigned short* __restrict__ q, unsigned short* __restrict__ k,
    unsigned short* __restrict__ vt) {
  __shared__ __align__(16) char smem[17408];
  short* As = (short*)smem;
  short* Bs = (short*)(smem + 8192);
  unsigned short* vlds = (unsigned short*)smem;  // [64 d][136] permuted s (V epilogue)
  const int t = threadIdx.x;
  const int wave = t >> 6, lane = t & 63;
  const int quad = lane >> 4, l16 = lane & 15;
  const int wm = (wave >> 1) * 64, wn = (wave & 1) * 64;
  const int mbase = blockIdx.x * 128, nbase = blockIdx.y * 128;
  f32x4 acc[4][4];
#pragma unroll
  for (int i = 0; i < 4; ++i)
#pragma unroll
    for (int j = 0; j < 4; ++j) acc[i][j] = (f32x4)0.0f;
  gemm_core<1024>(A, Bt, mbase, nbase, As, Bs, wm, wn, quad, l16, t, acc);

  if (nbase < 2048) {
    // ---- Q/K scatter epilogue ----
#pragma unroll
    for (int n = 0; n < 4; ++n) {
      int col = nbase + wn + n * 16 + l16;      // 0..2047
      float bc = bias[col];
      int which = col >> 10, rem = col & 1023;  // wave-uniform per n
      int h = rem >> 6, d = rem & 63;
      unsigned short* dst = which ? k : q;
      float scale = which ? 1.0f : QSCALE;
#pragma unroll
      for (int m = 0; m < 4; ++m) {
#pragma unroll
        for (int r = 0; r < 4; ++r) {
          int row = mbase + wm + m * 16 + quad * 4 + r;
          int b = row >> 11, s = row & 2047;
          dst[(((size_t)(b * 16 + h)) * 2048 + s) * 64 + d] = f2bf((acc[m][n][r] + bc) * scale);
        }
      }
    }
  } else {
    // ---- V transpose epilogue: tau64 per 64-block ----
    const int b = mbase >> 11, s0 = mbase & 2047;
    const int vcb = nbase - 2048;  // 0..895, v-column base
    __syncthreads();               // hard fence before vlds reuses the GEMM stage region
#pragma unroll
    for (int half = 0; half < 2; ++half) {
      if (wn == half * 64) {
#pragma unroll
        for (int n = 0; n < 4; ++n) {
          int col_l = n * 16 + l16;  // d 0..63
          float bc = bias[nbase + half * 64 + col_l];
#pragma unroll
          for (int m = 0; m < 4; ++m)
#pragma unroll
            for (int r = 0; r < 4; ++r) {
              int row_l = wm + m * 16 + quad * 4 + r;  // s_local 0..127
              int idx = (row_l & 64) + ((row_l >> 5) & 1) * 32 +
                        ((row_l >> 2) & 3) * 8 + ((row_l >> 4) & 1) * 4 + (row_l & 3);
              vlds[col_l * 136 + idx] = f2bf(acc[m][n][r] + bc);
            }
        }
      }
      __syncthreads();
      int h = (vcb + half * 64) >> 6;  // head 0..15
      size_t obase = ((size_t)(b * 16 + h)) * 64 * 2048;
#pragma unroll
      for (int i = 0; i < 4; ++i) {
        int c = t + i * 256;
        int d_l = c >> 4, c16 = c & 15;
        short8 v = *(const short8*)&vlds[d_l * 136 + c16 * 8];
        *(short8*)&vt[obase + (size_t)d_l * 2048 + s0 + c16 * 8] = v;
      }
      __syncthreads();
    }
  }
}

// Proj: 64x128 tiles, grid (64,8) = 512 blocks (2/CU) — R8-proven correct+faster.
__global__ __launch_bounds__(256, 2) void gemm_proj(
    const short* __restrict__ A, const short* __restrict__ Bt, const float* __restrict__ bias,
    float* __restrict__ out) {
  __shared__ __align__(16) short As[64 * 32];
  __shared__ __align__(16) short Bs[128 * 32];
  const int t = threadIdx.x;
  const int wave = t >> 6, lane = t & 63;
  const int quad = lane >> 4, l16 = lane & 15;
  const int wm = (wave >> 1) * 32, wn = (wave & 1) * 64;
  const int mbase = blockIdx.x * 64, nbase = blockIdx.y * 128;
  f32x4 acc[2][4];
#pragma unroll
  for (int i = 0; i < 2; ++i)
#pragma unroll
    for (int j = 0; j < 4; ++j) acc[i][j] = (f32x4)0.0f;
  for (int kt = 0; kt < 32; ++kt) {
    {  // A: 64 rows x 4 chunks = 256 chunks, 1/thread
      int row = t >> 2, c4 = t & 3;
      gld16(A + (size_t)(mbase + row) * 1024 + kt * 32 + c4 * 8, (char*)As + t * 16);
    }
#pragma unroll
    for (int i = 0; i < 2; ++i) {  // B: 128 rows x 4 chunks = 512 chunks, 2/thread
      int c = t + i * 256;
      int row = c >> 2, c4 = c & 3;
      gld16(Bt + (size_t)(nbase + row) * 1024 + kt * 32 + c4 * 8, (char*)Bs + c * 16);
    }
    __syncthreads();
    short8 af[2], bf[4];
#pragma unroll
    for (int m = 0; m < 2; ++m)
      af[m] = *(const short8*)((const char*)As + (wm + m * 16 + l16) * 64 + quad * 16);
#pragma unroll
    for (int n = 0; n < 4; ++n)
      bf[n] = *(const short8*)((const char*)Bs + (wn + n * 16 + l16) * 64 + quad * 16);
#pragma unroll
    for (int m = 0; m < 2; ++m)
#pragma unroll
      for (int n = 0; n < 4; ++n)
        acc[m][n] = mfma_bf16(af[m], bf[n], acc[m][n]);
    __syncthreads();
  }
#pragma unroll
  for (int n = 0; n < 4; ++n) {
    int col = nbase + wn + n * 16 + l16;
    float bc = bias[col];
#pragma unroll
    for (int m = 0; m < 2; ++m)
#pragma unroll
      for (int r = 0; r < 4; ++r) {
        int row = mbase + wm + m * 16 + quad * 4 + r;
        out[(size_t)row * 1024 + col] = acc[m][n][r] + bc;
      }
  }
}

// ---------------------------------------------------------------- flash ----
// R19 = R16 exactly (best measured flash: 48.5us).
// 3-buffer 2-ahead pipeline with counted vmcnt: stage(kt+2) issued during
// iter kt; top of iter kt waits vmcnt(4) (stage(kt+1) stays in flight across
// the barrier — targets loads issued TWO iterations ago). mask loads kept
// OLDER than stage in the vmcnt queue via sched_barrier. Swapped-QK
// in-register softmax (no P in LDS), tau64 V', KVBLK=64, Br=128, grid (32,16).
__global__ __launch_bounds__(256, 2) void flash_attn(
    const short* __restrict__ Qg, const short* __restrict__ Kg, const short* __restrict__ Vtg,
    const float* __restrict__ mask, unsigned short* __restrict__ ctx) {
  __shared__ __align__(16) unsigned char smem[49152];
  // K bufs: [0,24576) three 8K; V bufs: [24576,49152) three 8K
  const int t = threadIdx.x;  // 0..255
  const int wave = t >> 6, lane = t & 63;
  const int quad = lane >> 4, l16 = lane & 15;
  const int bh = blockIdx.x, b = bh >> 4, h = bh & 15;
  const int qbase = blockIdx.y * 128;
  const size_t bh_off = (size_t)bh * 2048 * 64;

  // ---- Q stage (16 KB, overlaps Kbuf0/Kbuf1 region), then to registers ----
#pragma unroll
  for (int i = 0; i < 4; ++i) {
    int c = t + i * 256;
    int row = c >> 3, col = c & 7;
    gld16(Qg + bh_off + (size_t)(qbase + row) * 64 + (col ^ (row & 7)) * 8,
          (char*)smem + c * 16);
  }
  __syncthreads();
  short8 qf[2][2];  // [m-frag][ks]
#pragma unroll
  for (int mf = 0; mf < 2; ++mf)
#pragma unroll
    for (int ks = 0; ks < 2; ++ks) {
      int row = wave * 32 + mf * 16 + l16;
      qf[mf][ks] = *(const short8*)((const char*)smem +
                                    (row * 8 + ((ks * 4 + quad) ^ (l16 & 7))) * 16);
    }
  __syncthreads();  // all waves done reading Q before K staging reuses region

  // ---- loop-invariant LDS byte offsets (VGPR-resident) ----
  int koff[2][4];  // [ks][n]
#pragma unroll
  for (int ks = 0; ks < 2; ++ks)
#pragma unroll
    for (int n = 0; n < 4; ++n) {
      int row = n * 16 + l16;
      koff[ks][n] = (row * 8 + ((ks * 4 + quad) ^ (l16 & 7))) * 16;
    }
  int voff[2][4];  // [ks][db]
#pragma unroll
  for (int ks = 0; ks < 2; ++ks)
#pragma unroll
    for (int db = 0; db < 4; ++db) {
      int d = db * 16 + l16;
      voff[ks][db] = d * 128 + (((ks * 4 + quad) ^ (d & 7)) * 16);
    }

  // ---- staging source pointers (increment by constants each stage) ----
  const short* kgp[2];
  const short* vgp[2];
#pragma unroll
  for (int i = 0; i < 2; ++i) {
    int c = t + i * 256;
    int row = c >> 3, col = c & 7;
    kgp[i] = Kg + bh_off + (size_t)row * 64 + (col ^ (row & 7)) * 8;
    vgp[i] = Vtg + ((size_t)bh * 64 + row) * 2048 + (col ^ (row & 7)) * 8;
  }
  const float* mpt = mask + b * 2048 + quad * 4;

  auto stage_to = [&](char* kd, char* vd) {
#pragma unroll
    for (int i = 0; i < 2; ++i) {
      gld16(kgp[i], kd + (t + i * 256) * 16);
      gld16(vgp[i], vd + (t + i * 256) * 16);
    }
    kgp[0] += 4096; kgp[1] += 4096;  // 64 rows x 64 shorts
    vgp[0] += 64;   vgp[1] += 64;    // 64 shorts along s
  };

  f32x4 O[2][4];
  float l_part[2];
#pragma unroll
  for (int mf = 0; mf < 2; ++mf)
#pragma unroll
    for (int d = 0; d < 4; ++d) O[mf][d] = (f32x4)0.0f;
  l_part[0] = 0.0f;
  l_part[1] = 0.0f;

  char* const KB[3] = {(char*)smem, (char*)smem + 8192, (char*)smem + 16384};
  char* const VB[3] = {(char*)smem + 24576, (char*)smem + 32768, (char*)smem + 40960};

  // iteration body: barrier (caller does the vmcnt wait), mask, optional
  // stage(kt+2), QK, in-register softmax, PV. No trailing barrier.
  auto iter_body = [&](const char* Kc, const char* Vc, char* ksd, char* vsd,
                       bool doStage) {
    __builtin_amdgcn_s_barrier();
    __builtin_amdgcn_sched_barrier(0);  // no ds_read of buf[kt] above barrier

    float4 mq[4];
#pragma unroll
    for (int n = 0; n < 4; ++n) mq[n] = *(const float4*)(mpt + n * 16);
    mpt += 64;
    __builtin_amdgcn_sched_barrier(0);  // mask loads stay OLDER than stage

    if (doStage) stage_to(ksd, vsd);

    // ---- S^T = K @ Q^T (log2 domain); kf feeds BOTH m-frags ----
    f32x4 sa[2][4];
    __builtin_amdgcn_s_setprio(1);
#pragma unroll
    for (int n = 0; n < 4; ++n) {
      short8 kf = *(const short8*)(Kc + koff[0][n]);
      sa[0][n] = mfma_bf16(kf, qf[0][0], (f32x4)0.0f);
      sa[1][n] = mfma_bf16(kf, qf[1][0], (f32x4)0.0f);
    }
#pragma unroll
    for (int n = 0; n < 4; ++n) {
      short8 kf = *(const short8*)(Kc + koff[1][n]);
      sa[0][n] = mfma_bf16(kf, qf[0][1], sa[0][n]);
      sa[1][n] = mfma_bf16(kf, qf[1][1], sa[1][n]);
    }
    __builtin_amdgcn_s_setprio(0);

    // ---- softmax fully in-register: lane owns q=l16, k = n*16+quad*4+r ----
    short8 pa[2][2];
#pragma unroll
    for (int mf = 0; mf < 2; ++mf) {
      float rs = 0.0f;
#pragma unroll
      for (int n = 0; n < 4; ++n) {
#pragma unroll
        for (int r = 0; r < 4; ++r) {
          float p = __builtin_amdgcn_exp2f(__builtin_fmaf(mq[n][r], L2E, sa[mf][n][r]));
          rs += p;
          pa[mf][n >> 1][(n & 1) * 4 + r] = (short)f2bf(p);
        }
      }
      l_part[mf] += rs;
    }

    // ---- O += P @ V' (vf feeds BOTH m-frags) ----
    __builtin_amdgcn_s_setprio(1);
#pragma unroll
    for (int ks = 0; ks < 2; ++ks) {
#pragma unroll
      for (int db = 0; db < 4; ++db) {
        short8 vf = *(const short8*)(Vc + voff[ks][db]);
        O[0][db] = mfma_bf16(pa[0][ks], vf, O[0][db]);
        O[1][db] = mfma_bf16(pa[1][ks], vf, O[1][db]);
      }
    }
    __builtin_amdgcn_s_setprio(0);
  };

  // prologue: stage kt=0 and kt=1 (8 vmem ops outstanding)
  stage_to(KB[0], VB[0]);
  stage_to(KB[1], VB[1]);

#define VMW4 asm volatile("s_waitcnt vmcnt(4)" ::: "memory")
#define VMW0 asm volatile("s_waitcnt vmcnt(0)" ::: "memory")

#pragma unroll 1
  for (int kt3 = 0; kt3 < 30; kt3 += 3) {
    VMW4; iter_body(KB[0], VB[0], KB[2], VB[2], true);
    VMW4; iter_body(KB[1], VB[1], KB[0], VB[0], true);
    VMW4; iter_body(KB[2], VB[2], KB[1], VB[1], true);
  }
  // kt = 30 (buf 0, stage(32) doesn't exist), kt = 31 (buf 1, full drain)
  VMW4; iter_body(KB[0], VB[0], nullptr, nullptr, false);
  VMW0; iter_body(KB[1], VB[1], nullptr, nullptr, false);

#undef VMW4
#undef VMW0

  // ---- l reduce: sum over quads (lane bits 4,5), then transpose to O layout ----
  float lr[2];
#pragma unroll
  for (int mf = 0; mf < 2; ++mf) {
    float l = l_part[mf];
    l += __shfl_xor(l, 16);
    l += __shfl_xor(l, 32);
    lr[mf] = l;  // valid for q = l16 (all quads hold it)
  }
#pragma unroll
  for (int mf = 0; mf < 2; ++mf) {
#pragma unroll
    for (int r = 0; r < 4; ++r) {
      float lq = __shfl(lr[mf], quad * 4 + r);  // l for q-local = quad*4+r
      float inv = 1.0f / lq;
      int s = qbase + wave * 32 + mf * 16 + quad * 4 + r;
      size_t o = ((size_t)b * 2048 + s) * 1024 + h * 64;
#pragma unroll
      for (int db = 0; db < 4; ++db)
        ctx[o + db * 16 + l16] = f2bf(O[mf][db][r] * inv);
    }
  }
}

// ---------------------------------------------------------------- launch ----
extern "C" void kernel_launch(void* const* d_in, const int* in_sizes, int n_in,
                              void* d_out, int out_size, void* d_ws, size_t ws_size,
                              hipStream_t stream) {
  const float* x      = (const float*)d_in[0];
  const float* mask   = (const float*)d_in[1];
  const float* w_attn = (const float*)d_in[2];
  const float* b_attn = (const float*)d_in[3];
  const float* w_proj = (const float*)d_in[4];
  const float* b_proj = (const float*)d_in[5];
  float* out = (float*)d_out;

  char* ws = (char*)d_ws;
  const size_t MB = 1024 * 1024;
  short*          Xbf    = (short*)(ws);                     // 8 MB, reused as ctx
  short*          Wqkv_t = (short*)(ws + 8 * MB);            // 6 MB
  short*          Wprj_t = (short*)(ws + 14 * MB);           // 2 MB
  unsigned short* Qb     = (unsigned short*)(ws + 16 * MB);  // 8 MB
  unsigned short* Kb     = (unsigned short*)(ws + 24 * MB);  // 8 MB
  unsigned short* Vtb    = (unsigned short*)(ws + 32 * MB);  // 8 MB
  unsigned short* ctx    = (unsigned short*)Xbf;

  prep<<<5120, 256, 0, stream>>>(x, (unsigned short*)Xbf,
                                 w_attn, (unsigned short*)Wqkv_t,
                                 w_proj, (unsigned short*)Wprj_t);
  gemm_qkv<<<dim3(32, 24), 256, 0, stream>>>(Xbf, Wqkv_t, b_attn, Qb, Kb, Vtb);
  flash_attn<<<dim3(32, 16), 256, 0, stream>>>((const short*)Qb, (const short*)Kb,
                                               (const short*)Vtb, mask, ctx);
  gemm_proj<<<dim3(64, 8), 256, 0, stream>>>((const short*)ctx, Wprj_t, b_proj, out);
}